// Round 6
// baseline (148.729 us; speedup 1.0000x reference)
//
#include <hip/hip_runtime.h>
#include <hip/hip_bf16.h>
#include <math.h>

// ---------------------------------------------------------------------------
// Math note: softmax(A, axis=2) then sum(A, axis=2, keepdims=True) * V == V.
// Pipeline: X1 = LN(X + X@Wv + bv); out = LN(X1 + relu(X1@W1+b1)@W2 + b2)
//
// Round-6: 128xBN tiles, BK=32, 4-deep LDS buffer ring (prefetch distance
// ~2.5 K-tiles > HBM latency), frag ds_reads pipelined 1 K-tile ahead
// (explicit 2-set register rotation), 1 barrier per K-tile, counted vmcnt
// (never 0 mid-loop), zero-conflict XOR swizzle (round-2-verified), setprio.
// 2 blocks/CU retained (LDS 64KB / 56KB).
//  - GEMM1 (8192x 768x 768, BN=96): grid 512, nt=24
//  - GEMM2 (8192x3072x 768, BN=128): grid 1536, nt=24
//  - GEMM3 (8192x 768x3072, BN=96): grid 512, nt=96
// ---------------------------------------------------------------------------

typedef __bf16 bf16x8 __attribute__((ext_vector_type(8)));
typedef float f32x4 __attribute__((ext_vector_type(4)));

__device__ inline void gload_lds16(const __hip_bfloat16* g, void* lds) {
  __builtin_amdgcn_global_load_lds(
      (const __attribute__((address_space(1))) void*)g,
      (__attribute__((address_space(3))) void*)lds, 16, 0, 0);
}

__device__ inline float bf2f(unsigned short u) {
  union { unsigned int i; float f; } x;
  x.i = ((unsigned int)u) << 16;
  return x.f;
}

#define BARRIER() asm volatile("s_barrier" ::: "memory")

// C(MxN) = A(MxK) @ Bt(NxK)^T, 128 x BNv tile, BK=32, 4 waves (2x2).
// EPI==1: +bias +fp32 residual; EPI==2: +bias relu; EPI==3: +bias +bf16 resid
template <int BNv, int EPI>
__global__ __launch_bounds__(256, 2) void gemm128(
    const __hip_bfloat16* __restrict__ A, const __hip_bfloat16* __restrict__ Bt,
    __hip_bfloat16* __restrict__ C, const float* __restrict__ bias,
    const float* __restrict__ residf, const __hip_bfloat16* __restrict__ residb,
    int M, int N, int K) {
  constexpr int NF = BNv / 32;    // n-frags per wave (4 or 3)
  constexpr int BS2 = BNv * 64;   // bytes per B buffer (BK=32)
  // smem: A ring 4 x 8192, then B ring 4 x BS2
  __shared__ __align__(16) char smem[32768 + 4 * BS2];

  const int bid = blockIdx.x;
  const int mB = M / 128;
  const int rowBase = (bid % mB) * 128;  // row-fastest (L3-friendly, r4-tested)
  const int colBase = (bid / mB) * BNv;
  const int nt = K / 32;

  const int wv = threadIdx.x >> 6;
  const int lane = threadIdx.x & 63;
  const int wr = wv >> 1, wc = wv & 1;  // 2x2 waves
  const int l16 = lane & 15, lk = lane >> 4;
  const bool hasB = (BNv == 128) || (wv < 3);  // BN=96: B staged by waves 0-2
  const bool SW4 = hasB;  // stage-instrs per wave per K-tile: 4 if B, else 2

  // ---- staging map (pre-swizzled global source, linear LDS dest) ----
  // thread covers row sr=lane>>2 (of 16-row load), phys chunk pc=lane&3;
  // logical chunk = pc ^ ((sr>>1)&3)  [round-2-verified involution, BK=32]
  const int sr = lane >> 2;
  const int scol = ((lane & 3) ^ ((sr >> 1) & 3)) * 8;  // bf16 elems
  const __hip_bfloat16* gA = A + (size_t)(rowBase + wv * 32 + sr) * K + scol;
  const __hip_bfloat16* gB = Bt + (size_t)(colBase + wv * 32 + sr) * K + scol;

  auto STAGE = [&](int kt, int b) {
    const size_t ko = (size_t)kt * 32;
#pragma unroll
    for (int i = 0; i < 2; ++i)
      gload_lds16(gA + (size_t)i * 16 * K + ko,
                  smem + b * 8192 + (wv * 2 + i) * 1024);
    if (hasB) {
#pragma unroll
      for (int i = 0; i < 2; ++i)
        gload_lds16(gB + (size_t)i * 16 * K + ko,
                    smem + 32768 + b * BS2 + (wv * 2 + i) * 1024);
    }
  };

  auto WAITSTAGE = [&](int t) {
    if (t + 3 < nt) {        // stages for t+2, t+3 in flight
      if (SW4) asm volatile("s_waitcnt vmcnt(8)" ::: "memory");
      else     asm volatile("s_waitcnt vmcnt(4)" ::: "memory");
    } else if (t + 2 < nt) { // only t+2 in flight
      if (SW4) asm volatile("s_waitcnt vmcnt(4)" ::: "memory");
      else     asm volatile("s_waitcnt vmcnt(2)" ::: "memory");
    } else {
      asm volatile("s_waitcnt vmcnt(0)" ::: "memory");
    }
  };

  // ---- ds_read addressing (phys chunk = lk ^ ((l16>>1)&3)) ----
  const int aByte = (wr * 64 + l16) * 64;
  const int bByte = (wc * (BNv / 2) + l16) * 64;
  const int cph = (lk ^ ((l16 >> 1) & 3)) * 16;

  f32x4 acc[4][NF];
#pragma unroll
  for (int m = 0; m < 4; ++m)
#pragma unroll
    for (int n = 0; n < NF; ++n) acc[m][n] = (f32x4){0.f, 0.f, 0.f, 0.f};

  bf16x8 a0[4], b0[NF], a1[4], b1[NF];

  // prologue: stage tiles 0,1,2; wait tile 0 (own parts); barrier; read frags0
  STAGE(0, 0);
  STAGE(1, 1);
  STAGE(2, 2);
  if (SW4) asm volatile("s_waitcnt vmcnt(8)" ::: "memory");
  else     asm volatile("s_waitcnt vmcnt(4)" ::: "memory");
  BARRIER();
  {
    const char* pa = smem + aByte;
    const char* pb = smem + 32768 + bByte;
#pragma unroll
    for (int m = 0; m < 4; ++m) a0[m] = *(const bf16x8*)(pa + m * 1024 + cph);
#pragma unroll
    for (int n = 0; n < NF; ++n) b0[n] = *(const bf16x8*)(pb + n * 1024 + cph);
  }

  // Per iter t: [lgkm0: frags(t) landed] [stage t+3] [vmcnt: t+1 staged]
  // [barrier] [ds_read frags(t+1) -> NXT] [MFMA(t) on CUR]
#define ITER(T, CA, CB, NA, NB)                                               \
  {                                                                           \
    const int t_ = (T);                                                       \
    asm volatile("s_waitcnt lgkmcnt(0)" ::: "memory");                        \
    __builtin_amdgcn_sched_barrier(0);                                        \
    if (t_ + 3 < nt) STAGE(t_ + 3, (t_ + 3) & 3);                             \
    WAITSTAGE(t_);                                                            \
    BARRIER();                                                                \
    if (t_ + 1 < nt) {                                                        \
      const char* pa = smem + ((t_ + 1) & 3) * 8192 + aByte;                  \
      const char* pb = smem + 32768 + ((t_ + 1) & 3) * BS2 + bByte;           \
      _Pragma("unroll")                                                       \
      for (int m = 0; m < 4; ++m)                                             \
        NA[m] = *(const bf16x8*)(pa + m * 1024 + cph);                        \
      _Pragma("unroll")                                                       \
      for (int n = 0; n < NF; ++n)                                            \
        NB[n] = *(const bf16x8*)(pb + n * 1024 + cph);                        \
    }                                                                         \
    __builtin_amdgcn_sched_barrier(0);                                        \
    __builtin_amdgcn_s_setprio(1);                                            \
    _Pragma("unroll")                                                         \
    for (int m = 0; m < 4; ++m) {                                             \
      _Pragma("unroll")                                                       \
      for (int n = 0; n < NF; ++n)                                            \
        acc[m][n] = __builtin_amdgcn_mfma_f32_16x16x32_bf16(CA[m], CB[n],     \
                                                            acc[m][n], 0, 0,  \
                                                            0);               \
    }                                                                         \
    __builtin_amdgcn_s_setprio(0);                                            \
  }

  for (int t = 0; t < nt; t += 2) {
    ITER(t, a0, b0, a1, b1);
    ITER(t + 1, a1, b1, a0, b0);
  }
#undef ITER

  // epilogue: C/D layout col=lane&15, row=(lane>>4)*4+reg (verified m89)
#pragma unroll
  for (int m = 0; m < 4; ++m) {
#pragma unroll
    for (int n = 0; n < NF; ++n) {
#pragma unroll
      for (int j = 0; j < 4; ++j) {
        const int r = rowBase + wr * 64 + m * 16 + lk * 4 + j;
        const int c = colBase + wc * (BNv / 2) + n * 16 + l16;
        const size_t idx = (size_t)r * N + c;
        float v = acc[m][n][j] + bias[c];
        if (EPI == 1) v += residf[idx];
        if (EPI == 2) v = fmaxf(v, 0.f);
        if (EPI == 3) v += __bfloat162float(residb[idx]);
        C[idx] = __float2bfloat16(v);
      }
    }
  }
}

// LayerNorm over D=768 (biased variance, no eps): one wave per row.
template <bool OUTF>
__global__ __launch_bounds__(256) void ln_simple(
    const __hip_bfloat16* __restrict__ Y, __hip_bfloat16* __restrict__ outb,
    float* __restrict__ outf) {
  const int wave = threadIdx.x >> 6, lane = threadIdx.x & 63;
  const size_t base = ((size_t)blockIdx.x * 4 + wave) * 768;

  float v[12];
  float s = 0.f, q = 0.f;
#pragma unroll
  for (int c = 0; c < 3; ++c) {
    const int col = c * 256 + lane * 4;
    ushort4 a = *reinterpret_cast<const ushort4*>(&Y[base + col]);
    float y0 = bf2f(a.x), y1 = bf2f(a.y), y2 = bf2f(a.z), y3 = bf2f(a.w);
    v[c * 4 + 0] = y0; v[c * 4 + 1] = y1; v[c * 4 + 2] = y2; v[c * 4 + 3] = y3;
    s += y0 + y1 + y2 + y3;
    q += y0 * y0 + y1 * y1 + y2 * y2 + y3 * y3;
  }
#pragma unroll
  for (int off = 32; off; off >>= 1) {
    s += __shfl_xor(s, off);
    q += __shfl_xor(q, off);
  }
  const float mu = s * (1.f / 768.f);
  const float rs = rsqrtf(q * (1.f / 768.f) - mu * mu);
#pragma unroll
  for (int c = 0; c < 3; ++c) {
    const int col = c * 256 + lane * 4;
    if (OUTF) {
      float4 o;
      o.x = (v[c * 4 + 0] - mu) * rs;
      o.y = (v[c * 4 + 1] - mu) * rs;
      o.z = (v[c * 4 + 2] - mu) * rs;
      o.w = (v[c * 4 + 3] - mu) * rs;
      *reinterpret_cast<float4*>(&outf[base + col]) = o;
    } else {
      __hip_bfloat16 h0 = __float2bfloat16((v[c * 4 + 0] - mu) * rs);
      __hip_bfloat16 h1 = __float2bfloat16((v[c * 4 + 1] - mu) * rs);
      __hip_bfloat16 h2 = __float2bfloat16((v[c * 4 + 2] - mu) * rs);
      __hip_bfloat16 h3 = __float2bfloat16((v[c * 4 + 3] - mu) * rs);
      ushort4 o;
      o.x = *reinterpret_cast<unsigned short*>(&h0);
      o.y = *reinterpret_cast<unsigned short*>(&h1);
      o.z = *reinterpret_cast<unsigned short*>(&h2);
      o.w = *reinterpret_cast<unsigned short*>(&h3);
      *reinterpret_cast<ushort4*>(&outb[base + col]) = o;
    }
  }
}

// Transpose-cast tile helper: W (KxN fp32) -> Wt (NxK bf16), 32x32 tile.
__device__ inline void tc_tile(const float* __restrict__ W,
                               __hip_bfloat16* __restrict__ Wt, int K, int N,
                               int n0, int k0, int t) {
  __shared__ float tile[32][33];
  const int tx = t & 31;
  const int ty = t >> 5;  // 0..7
#pragma unroll
  for (int i = 0; i < 32; i += 8)
    tile[ty + i][tx] = W[(size_t)(k0 + ty + i) * N + n0 + tx];
  __syncthreads();
#pragma unroll
  for (int i = 0; i < 32; i += 8)
    Wt[(size_t)(n0 + ty + i) * K + k0 + tx] = __float2bfloat16(tile[tx][ty + i]);
}

// Merged preprocessing: X cast (blocks [0,6144)), Wv^T [6144,6720),
// W1^T [6720,9024), W2^T [9024,11328).
__global__ __launch_bounds__(256) void prep_kernel(
    const float* __restrict__ X, const float* __restrict__ Wv,
    const float* __restrict__ W1, const float* __restrict__ W2,
    __hip_bfloat16* __restrict__ Xb, __hip_bfloat16* __restrict__ Wvt,
    __hip_bfloat16* __restrict__ W1t, __hip_bfloat16* __restrict__ W2t) {
  const int bid = blockIdx.x;
  const int t = threadIdx.x;
  if (bid < 6144) {  // cast 8192*768 fp32 -> bf16, 4/thread
    const int i = bid * 256 + t;
    float4 v = reinterpret_cast<const float4*>(X)[i];
    __hip_bfloat16 h0 = __float2bfloat16(v.x), h1 = __float2bfloat16(v.y);
    __hip_bfloat16 h2 = __float2bfloat16(v.z), h3 = __float2bfloat16(v.w);
    ushort4 o;
    o.x = *reinterpret_cast<unsigned short*>(&h0);
    o.y = *reinterpret_cast<unsigned short*>(&h1);
    o.z = *reinterpret_cast<unsigned short*>(&h2);
    o.w = *reinterpret_cast<unsigned short*>(&h3);
    reinterpret_cast<ushort4*>(Xb)[i] = o;
  } else if (bid < 6720) {  // Wv (768x768)
    const int idx = bid - 6144;
    tc_tile(Wv, Wvt, 768, 768, (idx % 24) * 32, (idx / 24) * 32, t);
  } else if (bid < 9024) {  // W1 (768x3072) -> W1t (3072x768)
    const int idx = bid - 6720;
    tc_tile(W1, W1t, 768, 3072, (idx % 96) * 32, (idx / 96) * 32, t);
  } else {  // W2 (3072x768) -> W2t (768x3072)
    const int idx = bid - 9024;
    tc_tile(W2, W2t, 3072, 768, (idx % 24) * 32, (idx / 24) * 32, t);
  }
}

extern "C" void kernel_launch(void* const* d_in, const int* in_sizes, int n_in,
                              void* d_out, int out_size, void* d_ws,
                              size_t ws_size, hipStream_t stream) {
  const float* X = (const float*)d_in[0];
  const float* Wv = (const float*)d_in[5];
  const float* bv = (const float*)d_in[6];
  const float* W1 = (const float*)d_in[7];
  const float* b1 = (const float*)d_in[8];
  const float* W2 = (const float*)d_in[9];
  const float* b2 = (const float*)d_in[10];
  float* out = (float*)d_out;

  const int M = 4 * 2048; // 8192 rows
  const int D = 768, H = 3072;

  // workspace layout (bytes), total 98,697,216:
  //  Xb   @ 0         (12,582,912)
  //  Wvt  @ 12582912  ( 1,179,648)
  //  W1t  @ 13762560  ( 4,718,592)
  //  W2t  @ 18481152  ( 4,718,592)
  //  Yb   @ 23199744  (12,582,912)   (reused as Y2b after LN1)
  //  X1b  @ 35782656  (12,582,912)
  //  Gb   @ 48365568  (50,331,648)
  char* ws = (char*)d_ws;
  __hip_bfloat16* Xb  = (__hip_bfloat16*)(ws);
  __hip_bfloat16* Wvt = (__hip_bfloat16*)(ws + 12582912);
  __hip_bfloat16* W1t = (__hip_bfloat16*)(ws + 13762560);
  __hip_bfloat16* W2t = (__hip_bfloat16*)(ws + 18481152);
  __hip_bfloat16* Yb  = (__hip_bfloat16*)(ws + 23199744);
  __hip_bfloat16* X1b = (__hip_bfloat16*)(ws + 35782656);
  __hip_bfloat16* Gb  = (__hip_bfloat16*)(ws + 48365568);
  __hip_bfloat16* Y2b = Yb;  // Yb dead after LN1

  prep_kernel<<<11328, 256, 0, stream>>>(X, Wv, W1, W2, Xb, Wvt, W1t, W2t);

  // Y = X@Wv + bv + X  (fused residual), grid 64*8 = 512, nt=24
  gemm128<96, 1><<<512, 256, 0, stream>>>(Xb, Wvt, Yb, bv, X, nullptr, M, D, D);
  // X1 = LN(Y)
  ln_simple<false><<<M / 4, 256, 0, stream>>>(Yb, X1b, nullptr);
  // G = relu(X1@W1 + b1), grid 64*24 = 1536, nt=24
  gemm128<128, 2><<<1536, 256, 0, stream>>>(X1b, W1t, Gb, b1, nullptr, nullptr,
                                            M, H, D);
  // Y2 = G@W2 + b2 + X1 (fused residual), grid 64*8 = 512, nt=96
  gemm128<96, 3><<<512, 256, 0, stream>>>(Gb, W2t, Y2b, b2, nullptr, X1b, M, D,
                                          H);
  // out = LN(Y2)
  ln_simple<true><<<M / 4, 256, 0, stream>>>(Y2b, nullptr, out);
}